// Round 1
// baseline (1774.475 us; speedup 1.0000x reference)
//
#include <hip/hip_runtime.h>
#include <hip/hip_bf16.h>
#include <stdint.h>

#define B_ 32
#define T_ 128
#define V_ 32000
#define E_ 256
#define HID_ 512

typedef float f32x4 __attribute__((ext_vector_type(4)));
typedef __bf16 bf16x8 __attribute__((ext_vector_type(8)));

// RNE float -> bf16 bits
static __device__ __forceinline__ unsigned short f2bf(float f) {
    unsigned int u = __float_as_uint(f);
    unsigned int r = (u + 0x7fffu + ((u >> 16) & 1u)) >> 16;
    return (unsigned short)r;
}

// ---------------------------------------------------------------------------
// K1: C[(t*B+b), :] = emb[x[b,t]] @ I + b1   (all f32)
// grid 256 WGs x 512 threads, 16 rows per WG
// ---------------------------------------------------------------------------
__global__ __launch_bounds__(512) void k_embed_proj(
    const int* __restrict__ x, const float* __restrict__ emb,
    const float* __restrict__ I, const float* __restrict__ b1,
    float* __restrict__ C) {
    __shared__ float e[16][E_];
    const int tid = threadIdx.x;
    const int row0 = blockIdx.x * 16;

    // stage 16 embedding rows into LDS (coalesced float4)
#pragma unroll
    for (int p = 0; p < 2; ++p) {
        int flat = p * 2048 + tid * 4;
        int i = flat >> 8;          // 0..15
        int c = flat & 255;
        int r = row0 + i;           // global row = t*B + b
        int t = r >> 5, b = r & 31;
        int xi = x[b * T_ + t];
        *(f32x4*)&e[i][c] = *(const f32x4*)(emb + (size_t)xi * E_ + c);
    }
    __syncthreads();

    float acc[16];
#pragma unroll
    for (int i = 0; i < 16; ++i) acc[i] = 0.f;
    const int j = tid; // output column 0..511

    for (int k4 = 0; k4 < E_ / 4; ++k4) {
        float Iv[4];
#pragma unroll
        for (int q = 0; q < 4; ++q) Iv[q] = I[(size_t)(k4 * 4 + q) * HID_ + j];
#pragma unroll
        for (int i = 0; i < 16; ++i) {
            f32x4 ev = *(const f32x4*)&e[i][k4 * 4];
            acc[i] += ev[0] * Iv[0];
            acc[i] += ev[1] * Iv[1];
            acc[i] += ev[2] * Iv[2];
            acc[i] += ev[3] * Iv[3];
        }
    }
    float bv = b1[j];
#pragma unroll
    for (int i = 0; i < 16; ++i)
        C[(size_t)(row0 + i) * HID_ + j] = acc[i] + bv;
}

// ---------------------------------------------------------------------------
// K2a: convert H (f32 [512][512]) -> bf16 bits, row-major
// ---------------------------------------------------------------------------
__global__ __launch_bounds__(256) void k_hconv(const float* __restrict__ H,
                                               unsigned short* __restrict__ Hb) {
    int idx = (blockIdx.x * 256 + threadIdx.x) * 4;
    f32x4 v = *(const f32x4*)(H + idx);
    unsigned int p0 = (unsigned)f2bf(v[0]) | ((unsigned)f2bf(v[1]) << 16);
    unsigned int p1 = (unsigned)f2bf(v[2]) | ((unsigned)f2bf(v[3]) << 16);
    uint2 pp; pp.x = p0; pp.y = p1;
    *(uint2*)(Hb + idx) = pp;
}

// ---------------------------------------------------------------------------
// K2b: transpose + convert U (f32 [512][32000]) -> Ut (bf16 [32000][512])
// grid (500, 8), 64x64 tiles
// ---------------------------------------------------------------------------
__global__ __launch_bounds__(256) void k_transpose(const float* __restrict__ U,
                                                   unsigned short* __restrict__ Ut) {
    __shared__ float tile[64][65];
    const int tid = threadIdx.x;
    const int n0 = blockIdx.x * 64;
    const int k0 = blockIdx.y * 64;
    const int c = tid & 63;
    const int r = tid >> 6; // 0..3
#pragma unroll
    for (int it = 0; it < 16; ++it) {
        int kk = it * 4 + r;
        tile[kk][c] = U[(size_t)(k0 + kk) * V_ + n0 + c];
    }
    __syncthreads();
#pragma unroll
    for (int it = 0; it < 16; ++it) {
        int nn = it * 4 + r;
        Ut[(size_t)(n0 + nn) * HID_ + k0 + c] = f2bf(tile[c][nn]);
    }
}

// ---------------------------------------------------------------------------
// K3: recurrence. grid = B_ (32), block = 512. One WG per batch row.
// h kept in LDS (f32). H streamed as bf16 each step (unpack in VALU).
// thread = (kg 0..7, cg 0..63): owns cols 8*cg..8*cg+7, k-range kg*64..+63.
// Partial sums reduced through LDS ps[8][512].
// ---------------------------------------------------------------------------
__global__ __launch_bounds__(512) void k_recur(
    const float* __restrict__ C, const unsigned short* __restrict__ Hb,
    const float* __restrict__ init, unsigned short* __restrict__ hsb,
    float* __restrict__ lastState) {
    __shared__ float h[HID_];
    __shared__ float ps[8][HID_];
    const int tid = threadIdx.x;
    const int b = blockIdx.x;
    const int kg = tid >> 6;
    const int cg = tid & 63;
    const int j0 = cg * 8;
    const int kbase = kg * 64;

    h[tid] = init[b * HID_ + tid];
    __syncthreads();

    for (int t = 0; t < T_; ++t) {
        float cv = C[((size_t)t * B_ + b) * HID_ + tid]; // issue early
        float a0 = 0, a1 = 0, a2 = 0, a3 = 0, a4 = 0, a5 = 0, a6 = 0, a7 = 0;
#pragma unroll 4
        for (int k4 = 0; k4 < 16; ++k4) {
            f32x4 hv = *(const f32x4*)&h[kbase + k4 * 4];
#pragma unroll
            for (int q = 0; q < 4; ++q) {
                const uint4 u = *(const uint4*)(Hb + (size_t)(kbase + k4 * 4 + q) * HID_ + j0);
                float hq = hv[q];
                a0 += hq * __uint_as_float(u.x << 16);
                a1 += hq * __uint_as_float(u.x & 0xffff0000u);
                a2 += hq * __uint_as_float(u.y << 16);
                a3 += hq * __uint_as_float(u.y & 0xffff0000u);
                a4 += hq * __uint_as_float(u.z << 16);
                a5 += hq * __uint_as_float(u.z & 0xffff0000u);
                a6 += hq * __uint_as_float(u.w << 16);
                a7 += hq * __uint_as_float(u.w & 0xffff0000u);
            }
        }
        f32x4 w0 = {a0, a1, a2, a3};
        f32x4 w1 = {a4, a5, a6, a7};
        *(f32x4*)&ps[kg][j0] = w0;
        *(f32x4*)&ps[kg][j0 + 4] = w1;
        __syncthreads(); // ps visible; all h reads of this step complete

        float v = cv;
#pragma unroll
        for (int g = 0; g < 8; ++g) v += ps[g][tid];
        v = fmaxf(v, 0.f);
        h[tid] = v;
        hsb[((size_t)t * B_ + b) * HID_ + tid] = f2bf(v);
        __syncthreads(); // h visible for next step
    }
    lastState[b * HID_ + tid] = h[tid];
}

// ---------------------------------------------------------------------------
// K4: logits = hs[4096x512](bf16) @ Ut^T[512x32000](bf16, stored [N][K]) + b2
// out[(b*T+t)*V + v], f32. 128x128 tile, BK=64, 4 waves (2x2), 16x16x32 MFMA.
// Reg-staged LDS with +8 bf16 padding (2-way-bank-conflict only).
// grid (250, 32) so consecutive blocks share the A M-panel (L2-friendly).
// ---------------------------------------------------------------------------
#define LDK 72
__global__ __launch_bounds__(256) void k_gemm(
    const unsigned short* __restrict__ A, const unsigned short* __restrict__ Bt,
    const float* __restrict__ b2, float* __restrict__ out) {
    __shared__ unsigned short As[128 * LDK];
    __shared__ unsigned short Bs[128 * LDK];
    const int tid = threadIdx.x;
    const int l = tid & 63;
    const int w = tid >> 6;
    const int wm = w >> 1, wn = w & 1;
    const int n0 = blockIdx.x * 128;
    const int m0 = blockIdx.y * 128;

    f32x4 acc[4][4] = {};

    for (int kt = 0; kt < 8; ++kt) {
        const int kk = kt * 64;
        uint4 ra[4], rb[4];
#pragma unroll
        for (int i = 0; i < 4; ++i) {
            int flat = i * 256 + tid;
            int row = flat >> 3;
            int c8 = (flat & 7) * 8;
            ra[i] = *(const uint4*)(A + (size_t)(m0 + row) * HID_ + kk + c8);
            rb[i] = *(const uint4*)(Bt + (size_t)(n0 + row) * HID_ + kk + c8);
        }
        __syncthreads(); // previous tile's compute done before overwrite
#pragma unroll
        for (int i = 0; i < 4; ++i) {
            int flat = i * 256 + tid;
            int row = flat >> 3;
            int c8 = (flat & 7) * 8;
            *(uint4*)(As + row * LDK + c8) = ra[i];
            *(uint4*)(Bs + row * LDK + c8) = rb[i];
        }
        __syncthreads();
#pragma unroll
        for (int ks = 0; ks < 2; ++ks) {
            bf16x8 af[4], bfr[4];
#pragma unroll
            for (int f = 0; f < 4; ++f) {
                af[f]  = *(const bf16x8*)(As + (wm * 64 + f * 16 + (l & 15)) * LDK + ks * 32 + (l >> 4) * 8);
                bfr[f] = *(const bf16x8*)(Bs + (wn * 64 + f * 16 + (l & 15)) * LDK + ks * 32 + (l >> 4) * 8);
            }
#pragma unroll
            for (int fm = 0; fm < 4; ++fm)
#pragma unroll
                for (int fn = 0; fn < 4; ++fn)
                    acc[fm][fn] = __builtin_amdgcn_mfma_f32_16x16x32_bf16(
                        af[fm], bfr[fn], acc[fm][fn], 0, 0, 0);
        }
    }

    // epilogue: D col = lane&15, row = (lane>>4)*4 + reg  [guide §3, m89]
    const int cl = l & 15;
    const int q4 = (l >> 4) * 4;
    float b2v[4];
#pragma unroll
    for (int fn = 0; fn < 4; ++fn) b2v[fn] = b2[n0 + wn * 64 + fn * 16 + cl];
#pragma unroll
    for (int fm = 0; fm < 4; ++fm) {
#pragma unroll
        for (int r = 0; r < 4; ++r) {
            int rg = m0 + wm * 64 + fm * 16 + q4 + r; // A-row = t*B + b
            int t = rg >> 5, b = rg & 31;
            float* orow = out + (size_t)(b * T_ + t) * V_ + n0 + wn * 64 + cl;
#pragma unroll
            for (int fn = 0; fn < 4; ++fn)
                orow[fn * 16] = acc[fm][fn][r] + b2v[fn];
        }
    }
}

// ---------------------------------------------------------------------------
extern "C" void kernel_launch(void* const* d_in, const int* in_sizes, int n_in,
                              void* d_out, int out_size, void* d_ws, size_t ws_size,
                              hipStream_t stream) {
    const int* x      = (const int*)d_in[0];
    const float* init = (const float*)d_in[1];
    const float* emb  = (const float*)d_in[2];
    const float* H    = (const float*)d_in[3];
    const float* I    = (const float*)d_in[4];
    const float* b1   = (const float*)d_in[5];
    const float* U    = (const float*)d_in[6];
    const float* b2   = (const float*)d_in[7];
    float* out = (float*)d_out;

    // workspace layout (≈46.5 MB total):
    //   [0,8MB)    C      f32  [T*B][512]
    //   [8,12MB)   hsb    bf16 [T*B][512]
    //   [12,~45MB) Ut     bf16 [32000][512]
    //   [46MB,..)  Hb     bf16 [512][512]
    char* ws = (char*)d_ws;
    float* C            = (float*)ws;
    unsigned short* hsb = (unsigned short*)(ws + ((size_t)8 << 20));
    unsigned short* Ut  = (unsigned short*)(ws + ((size_t)12 << 20));
    unsigned short* Hb  = (unsigned short*)(ws + ((size_t)46 << 20));

    k_embed_proj<<<256, 512, 0, stream>>>(x, emb, I, b1, C);
    k_hconv<<<(HID_ * HID_) / (256 * 4), 256, 0, stream>>>(H, Hb);
    k_transpose<<<dim3(500, 8), 256, 0, stream>>>(U, Ut);
    k_recur<<<B_, 512, 0, stream>>>(C, Hb, init, hsb, out + (size_t)B_ * T_ * V_);
    k_gemm<<<dim3(250, 32), 256, 0, stream>>>(hsb, Ut, b2, out);
}